// Round 1
// baseline (1495.218 us; speedup 1.0000x reference)
//
#include <hip/hip_runtime.h>

#define T 20
#define N1 65536
#define N2 4096

// GEMM tiling: each block = 256 threads, each thread owns 4 columns (float4).
// Block covers COLS_PER_BLOCK=1024 columns x ROWS_PER_BLOCK=512 rows.
// Grid = (N1/512) row-chunks * (N2/1024)=4 col-chunks = 512 blocks.
#define ROWS_PER_BLOCK 512
#define COLS_PER_BLOCK 1024

// ---------------------------------------------------------------------------
// Kernel 1: layer-1 ensemble simulation. One thread per neuron, loops all T
// steps (layer-1 dynamics are independent of layer-2). Writes spike floats
// (0.0/1.0) to S laid out [N1][T] so the GEMM can scalar-load a row's 20
// spike values contiguously.
// ---------------------------------------------------------------------------
__global__ __launch_bounds__(256) void layer1_kernel(const float* __restrict__ x_seq,
                                                     float* __restrict__ S) {
    int i = blockIdx.x * blockDim.x + threadIdx.x;
    float act = 0.0f, gain = 1.0f, thr = 1.0f, freq = 0.0f;
    float sf_arr[T];
#pragma unroll
    for (int t = 0; t < T; ++t) {
        float x = x_seq[t * N1 + i];
        // gain = gain + (1 - gain) * 0.2
        gain = __fadd_rn(gain, __fmul_rn(__fsub_rn(1.0f, gain), 0.2f));
        // act = 0.9*act + x*gain + 0.05   (left-assoc, no fma, to match np)
        act = __fadd_rn(__fadd_rn(__fmul_rn(0.9f, act), __fmul_rn(x, gain)), 0.05f);
        bool sp = act > thr;
        float sf = sp ? 1.0f : 0.0f;
        // freq = 0.95*freq + 0.05*sf
        freq = __fadd_rn(__fmul_rn(0.95f, freq), __fmul_rn(0.05f, sf));
        if (freq > 0.1f)       thr = __fadd_rn(thr, 0.05f);
        else if (freq < 0.1f)  thr = __fdiv_rn(thr, 1.05f);
        gain = sp ? -0.3f : gain;
        act  = sp ? 0.0f  : act;
        sf_arr[t] = sf;
    }
#pragma unroll
    for (int t = 0; t < T; ++t) S[i * T + t] = sf_arr[t];
}

// ---------------------------------------------------------------------------
// Kernel 2: Y[T,N2] = S[T,N1] @ W[N1,N2] streaming W exactly once.
// Thread: 4 columns (one float4 of W per row), 20 float4 accumulators in
// registers. S row values are block-uniform -> compiler emits s_loads.
// Partials combined with fp32 atomicAdd into Y (zeroed by memsetAsync).
// ---------------------------------------------------------------------------
__global__ __launch_bounds__(256) void spike_gemm_kernel(const float* __restrict__ W,
                                                         const float* __restrict__ S,
                                                         float* __restrict__ Y) {
    int cb = blockIdx.x & 3;   // 4 column chunks
    int rb = blockIdx.x >> 2;  // row chunks
    int j  = cb * COLS_PER_BLOCK + threadIdx.x * 4;
    int i0 = rb * ROWS_PER_BLOCK;

    float4 acc[T];
#pragma unroll
    for (int t = 0; t < T; ++t) acc[t] = make_float4(0.f, 0.f, 0.f, 0.f);

    const float4* Wp = reinterpret_cast<const float4*>(W + (size_t)i0 * N2 + j);
    const float*  Sp = S + (size_t)i0 * T;

#pragma unroll 4
    for (int r = 0; r < ROWS_PER_BLOCK; ++r) {
        float4 w = Wp[(size_t)r * (N2 / 4)];
        const float* s = Sp + r * T;
#pragma unroll
        for (int t = 0; t < T; ++t) {
            float sv = s[t];          // 0.0 or 1.0 -> acc += w*sv is exact
            acc[t].x += w.x * sv;
            acc[t].y += w.y * sv;
            acc[t].z += w.z * sv;
            acc[t].w += w.w * sv;
        }
    }

#pragma unroll
    for (int t = 0; t < T; ++t) {
        float* y = Y + t * N2 + j;
        atomicAdd(y + 0, acc[t].x);
        atomicAdd(y + 1, acc[t].y);
        atomicAdd(y + 2, acc[t].z);
        atomicAdd(y + 3, acc[t].w);
    }
}

// ---------------------------------------------------------------------------
// Kernel 3: layer-2 ensemble simulation. One thread per output neuron
// (neurons independent), loops T steps, records post-reset activation.
// ---------------------------------------------------------------------------
__global__ __launch_bounds__(256) void layer2_kernel(const float* __restrict__ Y,
                                                     float* __restrict__ out) {
    int j = blockIdx.x * blockDim.x + threadIdx.x;
    float act = 0.0f, gain = 1.0f, thr = 1.0f, freq = 0.0f;
#pragma unroll
    for (int t = 0; t < T; ++t) {
        float y = Y[t * N2 + j];
        gain = __fadd_rn(gain, __fmul_rn(__fsub_rn(1.0f, gain), 0.2f));
        act = __fadd_rn(__fadd_rn(__fmul_rn(0.9f, act), __fmul_rn(y, gain)), 0.05f);
        bool sp = act > thr;
        float sf = sp ? 1.0f : 0.0f;
        freq = __fadd_rn(__fmul_rn(0.95f, freq), __fmul_rn(0.05f, sf));
        if (freq > 0.1f)       thr = __fadd_rn(thr, 0.05f);
        else if (freq < 0.1f)  thr = __fdiv_rn(thr, 1.05f);
        gain = sp ? -0.3f : gain;
        act  = sp ? 0.0f  : act;
        out[t * N2 + j] = act;   // post-reset activation, per reference
    }
}

extern "C" void kernel_launch(void* const* d_in, const int* in_sizes, int n_in,
                              void* d_out, int out_size, void* d_ws, size_t ws_size,
                              hipStream_t stream) {
    const float* x_seq = (const float*)d_in[0];   // [T, N1]
    const float* W     = (const float*)d_in[1];   // [N1, N2]
    float* out = (float*)d_out;                   // [T, N2]

    // Workspace layout: S float[N1][T] (5,242,880 B), then Y float[T][N2].
    float* S = (float*)d_ws;
    float* Y = (float*)((char*)d_ws + (size_t)N1 * T * sizeof(float));

    // Y must be zeroed every call (ws is re-poisoned to 0xAA by the harness).
    hipMemsetAsync(Y, 0, (size_t)T * N2 * sizeof(float), stream);

    layer1_kernel<<<N1 / 256, 256, 0, stream>>>(x_seq, S);

    int gemm_blocks = (N1 / ROWS_PER_BLOCK) * (N2 / COLS_PER_BLOCK);  // 512
    spike_gemm_kernel<<<gemm_blocks, 256, 0, stream>>>(W, S, Y);

    layer2_kernel<<<N2 / 256, 256, 0, stream>>>(Y, out);
}

// Round 2
// 1436.832 us; speedup vs baseline: 1.0406x; 1.0406x over previous
//
#include <hip/hip_runtime.h>
#include <stdint.h>

#define T 20
#define N1 65536
#define N2 4096

// GEMM tiling: 256 threads/block, each thread owns 4 columns (float4).
// Block covers 1024 columns x RPB rows. Grid = (N1/RPB) * (N2/1024) blocks.
#define RPB 256   // rows per block (split-K chunk)
#define NCHUNK (N1 / RPB)          // 256
#define CPB 1024

// ---------------------------------------------------------------------------
// Kernel 1: layer-1 ensemble sim. One thread per neuron, all T steps
// (layer-1 dynamics independent of layer-2). Spikes packed as bit t of a
// uint32 per neuron -> GEMM reads one scalar dword per row.
// ---------------------------------------------------------------------------
__global__ __launch_bounds__(256) void layer1_kernel(const float* __restrict__ x_seq,
                                                     uint32_t* __restrict__ Sbits) {
    int i = blockIdx.x * blockDim.x + threadIdx.x;
    float act = 0.0f, gain = 1.0f, thr = 1.0f, freq = 0.0f;
    uint32_t bits = 0;
#pragma unroll
    for (int t = 0; t < T; ++t) {
        float x = x_seq[t * N1 + i];
        gain = __fadd_rn(gain, __fmul_rn(__fsub_rn(1.0f, gain), 0.2f));
        act = __fadd_rn(__fadd_rn(__fmul_rn(0.9f, act), __fmul_rn(x, gain)), 0.05f);
        bool sp = act > thr;
        float sf = sp ? 1.0f : 0.0f;
        freq = __fadd_rn(__fmul_rn(0.95f, freq), __fmul_rn(0.05f, sf));
        if (freq > 0.1f)       thr = __fadd_rn(thr, 0.05f);
        else if (freq < 0.1f)  thr = __fdiv_rn(thr, 1.05f);
        gain = sp ? -0.3f : gain;
        act  = sp ? 0.0f  : act;
        if (sp) bits |= (1u << t);
    }
    Sbits[i] = bits;
}

// ---------------------------------------------------------------------------
// Kernel 2: split-K spike GEMM. P[chunk][T][N2] partials, streaming W once.
// Spike mask is block-uniform (scalar load + scalar branches): only spiked
// timesteps pay 4 v_add each. W loads unconditional (streaming, pipelined
// via manual 4x unroll).
// ---------------------------------------------------------------------------
__device__ __forceinline__ void accum_row(float4* acc, uint32_t bits, const float4& w) {
    if (bits) {
#pragma unroll
        for (int t = 0; t < T; ++t) {
            if (bits & (1u << t)) {
                acc[t].x += w.x; acc[t].y += w.y; acc[t].z += w.z; acc[t].w += w.w;
            }
        }
    }
}

__global__ __launch_bounds__(256) void spike_gemm_kernel(const float* __restrict__ W,
                                                         const uint32_t* __restrict__ Sb,
                                                         float* __restrict__ P) {
    int cb = blockIdx.x & 3;   // 4 column chunks
    int rb = blockIdx.x >> 2;  // NCHUNK row chunks
    int j  = cb * CPB + threadIdx.x * 4;
    int i0 = rb * RPB;

    float4 acc[T];
#pragma unroll
    for (int t = 0; t < T; ++t) acc[t] = make_float4(0.f, 0.f, 0.f, 0.f);

    const float4* Wp = reinterpret_cast<const float4*>(W + (size_t)i0 * N2 + j);

    for (int r = 0; r < RPB; r += 4) {
        // issue all loads first (4 W lines in flight + scalar mask loads)
        uint32_t b0 = Sb[i0 + r + 0];
        uint32_t b1 = Sb[i0 + r + 1];
        uint32_t b2 = Sb[i0 + r + 2];
        uint32_t b3 = Sb[i0 + r + 3];
        float4 w0 = Wp[(size_t)(r + 0) * (N2 / 4)];
        float4 w1 = Wp[(size_t)(r + 1) * (N2 / 4)];
        float4 w2 = Wp[(size_t)(r + 2) * (N2 / 4)];
        float4 w3 = Wp[(size_t)(r + 3) * (N2 / 4)];
        accum_row(acc, b0, w0);
        accum_row(acc, b1, w1);
        accum_row(acc, b2, w2);
        accum_row(acc, b3, w3);
    }

    // Coalesced float4 stores of this chunk's partial tile.
    float* Pp = P + (size_t)rb * T * N2;
#pragma unroll
    for (int t = 0; t < T; ++t) {
        *reinterpret_cast<float4*>(Pp + (size_t)t * N2 + j) = acc[t];
    }
}

// ---------------------------------------------------------------------------
// Kernel 3: reduce partials. One thread per (t, j) output cell, sums the
// NCHUNK partials (coalesced in j across lanes).
// ---------------------------------------------------------------------------
__global__ __launch_bounds__(256) void reduce_kernel(const float* __restrict__ P,
                                                     float* __restrict__ Y) {
    int idx = blockIdx.x * blockDim.x + threadIdx.x;  // over T*N2
    float s = 0.0f;
#pragma unroll 8
    for (int c = 0; c < NCHUNK; ++c) s += P[(size_t)c * T * N2 + idx];
    Y[idx] = s;
}

// ---------------------------------------------------------------------------
// Kernel 4: layer-2 ensemble sim. One thread per output neuron.
// ---------------------------------------------------------------------------
__global__ __launch_bounds__(256) void layer2_kernel(const float* __restrict__ Y,
                                                     float* __restrict__ out) {
    int j = blockIdx.x * blockDim.x + threadIdx.x;
    float act = 0.0f, gain = 1.0f, thr = 1.0f, freq = 0.0f;
#pragma unroll
    for (int t = 0; t < T; ++t) {
        float y = Y[t * N2 + j];
        gain = __fadd_rn(gain, __fmul_rn(__fsub_rn(1.0f, gain), 0.2f));
        act = __fadd_rn(__fadd_rn(__fmul_rn(0.9f, act), __fmul_rn(y, gain)), 0.05f);
        bool sp = act > thr;
        float sf = sp ? 1.0f : 0.0f;
        freq = __fadd_rn(__fmul_rn(0.95f, freq), __fmul_rn(0.05f, sf));
        if (freq > 0.1f)       thr = __fadd_rn(thr, 0.05f);
        else if (freq < 0.1f)  thr = __fdiv_rn(thr, 1.05f);
        gain = sp ? -0.3f : gain;
        act  = sp ? 0.0f  : act;
        out[t * N2 + j] = act;
    }
}

extern "C" void kernel_launch(void* const* d_in, const int* in_sizes, int n_in,
                              void* d_out, int out_size, void* d_ws, size_t ws_size,
                              hipStream_t stream) {
    const float* x_seq = (const float*)d_in[0];   // [T, N1]
    const float* W     = (const float*)d_in[1];   // [N1, N2]
    float* out = (float*)d_out;                   // [T, N2]

    // Workspace layout:
    //   Sbits uint32[N1]                      (256 KB)
    //   P     float[NCHUNK][T][N2]            (84 MB)
    //   Y     float[T][N2]                    (328 KB)
    uint32_t* Sbits = (uint32_t*)d_ws;
    float* P = (float*)((char*)d_ws + (size_t)N1 * sizeof(uint32_t));
    float* Y = P + (size_t)NCHUNK * T * N2;

    layer1_kernel<<<N1 / 256, 256, 0, stream>>>(x_seq, Sbits);

    int gemm_blocks = NCHUNK * (N2 / CPB);  // 1024
    spike_gemm_kernel<<<gemm_blocks, 256, 0, stream>>>(W, Sbits, P);

    reduce_kernel<<<(T * N2) / 256, 256, 0, stream>>>(P, Y);

    layer2_kernel<<<N2 / 256, 256, 0, stream>>>(Y, out);
}